// Round 3
// baseline (383.353 us; speedup 1.0000x reference)
//
#include <hip/hip_runtime.h>
#include <math.h>

// OFPenalty round 3: power-iteration eigen-penalty on AAT = W W^T, never
// materializing AAT. 12 row-contiguous passes over A (L3-resident after the
// first), two kernels per double-matvec:
//   k_u: u = W^T x_hat   (block = 32-row stripe -> 100 KB contiguous span)
//   k_a: v = W u         (wave per row, 3136-B contiguous reads)
// Round-2 lesson: 128-B scattered granules ran at 1.8 TB/s; contiguity wins.
// A: (64, 512, 28, 28) fp32 -> W: (64, 512, 784). x0: (64, 512, 1).

#define BB 64
#define CC 512
#define DD 784
#define STRIPES 16
#define RPS 32          // rows per stripe = 512/16
#define FEPS 1e-12f

// acc[b*16+k]: 0 ss0, 1..4 ss1..ss4, 5 num, 6 den, 7 ssy, 8 largest,
//              9 dotwx, 10 den2

__global__ void k_zero(float* __restrict__ p, int n) {
    int i = blockIdx.x * 256 + threadIdx.x;
    if (i < n) p[i] = 0.0f;
}

__device__ __forceinline__ float blk_reduce(float s, float* red) {
    for (int off = 32; off; off >>= 1) s += __shfl_down(s, off, 64);
    int w = threadIdx.x >> 6;
    if ((threadIdx.x & 63) == 0) red[w] = s;
    __syncthreads();
    float t = red[0] + red[1] + red[2] + red[3];
    __syncthreads();
    return t;
}

// ss0 = ||x0_b||^2
__global__ void k_init(const float* __restrict__ x0, float* __restrict__ acc) {
    __shared__ float red[4];
    int b = blockIdx.x;
    const float* x = x0 + (size_t)b * CC;
    float v0 = x[threadIdx.x], v1 = x[threadIdx.x + 256];
    float t = blk_reduce(v0 * v0 + v1 * v1, red);
    if (threadIdx.x == 0) acc[b * 16 + 0] = t;
}

// u[b,:] += sum_{c in stripe} A[b,c,:] * (x[b,c] * rn).  Contiguous 100 KB
// span per block. grid (STRIPES, BB) x 256.
__global__ __launch_bounds__(256, 4)
void k_u(const float* __restrict__ A, const float* __restrict__ xin,
         const float* __restrict__ acc, int ss_k, float* __restrict__ uout) {
    __shared__ float up[4][800];           // 784 padded to 800
    int b = blockIdx.y, stripe = blockIdx.x;
    int wave = threadIdx.x >> 6, lane = threadIdx.x & 63;
    int c0 = stripe * RPS;
    float rn = 1.0f / fmaxf(sqrtf(acc[b * 16 + ss_k]), FEPS);
    const float* xp = xin + (size_t)b * CC;

    float xv[8];
#pragma unroll
    for (int i = 0; i < 8; i++) xv[i] = xp[c0 + wave + 4 * i] * rn;

    const float4* Abase = (const float4*)(A + ((size_t)b * CC + c0) * DD);
    float4 a0 = make_float4(0.f, 0.f, 0.f, 0.f), a1 = a0, a2 = a0, a3 = a0;
#pragma unroll 4
    for (int i = 0; i < 8; i++) {
        int r = wave + 4 * i;
        const float4* row = Abase + (size_t)r * 196;   // 784/4
        float xc = xv[i];
        float4 f0 = row[lane], f1 = row[lane + 64], f2 = row[lane + 128];
        a0.x += f0.x * xc; a0.y += f0.y * xc; a0.z += f0.z * xc; a0.w += f0.w * xc;
        a1.x += f1.x * xc; a1.y += f1.y * xc; a1.z += f1.z * xc; a1.w += f1.w * xc;
        a2.x += f2.x * xc; a2.y += f2.y * xc; a2.z += f2.z * xc; a2.w += f2.w * xc;
        if (lane < 4) {
            float4 f3 = row[192 + lane];
            a3.x += f3.x * xc; a3.y += f3.y * xc; a3.z += f3.z * xc; a3.w += f3.w * xc;
        }
    }
    int d4 = 4 * lane;
    *(float4*)&up[wave][d4]       = a0;
    *(float4*)&up[wave][d4 + 256] = a1;
    *(float4*)&up[wave][d4 + 512] = a2;
    if (lane < 4) *(float4*)&up[wave][d4 + 768] = a3;
    __syncthreads();
    float* uo = uout + (size_t)b * DD;
    for (int d = threadIdx.x; d < DD; d += 256) {
        float s = up[0][d] + up[1][d] + up[2][d] + up[3][d];
        atomicAdd(&uo[d], s);
    }
}

// v[b,c] = <A[b,c,:], u[b,:]>; one wave per row c. grid (128, BB) x 256.
// mode 0: acc[k0] += v^2
// mode 1: acc[k0] += v*xn, acc[k0+1] += xn^2, xn = xvec2 * rsqrt(acc[ss_k2])
__global__ void k_a(const float* __restrict__ A, const float* __restrict__ u,
                    float* __restrict__ vout, float* __restrict__ acc,
                    int mode, int k0,
                    const float* __restrict__ xvec2, int ss_k2) {
    int b = blockIdx.y;
    int wave = threadIdx.x >> 6;
    int lane = threadIdx.x & 63;
    int c = blockIdx.x * 4 + wave;
    const float4* ap = (const float4*)(A + (size_t)(b * CC + c) * DD);
    const float4* up = (const float4*)(u + (size_t)b * DD);
    float s = 0.0f;
#pragma unroll
    for (int k = 0; k < 3; ++k) {
        float4 a4 = ap[lane + 64 * k];
        float4 u4 = up[lane + 64 * k];
        s += a4.x * u4.x + a4.y * u4.y + a4.z * u4.z + a4.w * u4.w;
    }
    if (lane < 4) {                        // 196 = 3*64 + 4 tail
        float4 a4 = ap[192 + lane];
        float4 u4 = up[192 + lane];
        s += a4.x * u4.x + a4.y * u4.y + a4.z * u4.z + a4.w * u4.w;
    }
    for (int off = 32; off; off >>= 1) s += __shfl_down(s, off, 64);
    __shared__ float p0[4], p1[4];
    if (lane == 0) {
        if (vout) vout[(size_t)b * CC + c] = s;
        if (mode == 0) {
            p0[wave] = s * s; p1[wave] = 0.0f;
        } else {
            float denom2 = fmaxf(sqrtf(acc[b * 16 + ss_k2]), FEPS);
            float xn = xvec2[(size_t)b * CC + c] / denom2;
            p0[wave] = s * xn;
            p1[wave] = xn * xn;
        }
    }
    __syncthreads();
    if (threadIdx.x == 0) {
        atomicAdd(&acc[b * 16 + k0], p0[0] + p0[1] + p0[2] + p0[3]);
        if (mode == 1)
            atomicAdd(&acc[b * 16 + k0 + 1], p1[0] + p1[1] + p1[2] + p1[3]);
    }
}

// largest = num/den; y = t5 - largest * (t4/||t4||); ssy, largest -> acc
__global__ void k_mid(const float* __restrict__ t4, const float* __restrict__ t5,
                      float* __restrict__ acc, float* __restrict__ y) {
    __shared__ float red[4];
    int b = blockIdx.x;
    float num = acc[b * 16 + 5], den = acc[b * 16 + 6];
    float largest = num / den;
    float rn = 1.0f / fmaxf(sqrtf(acc[b * 16 + 4]), FEPS);
    const float* p4 = t4 + (size_t)b * CC;
    const float* p5 = t5 + (size_t)b * CC;
    float* yp = y + (size_t)b * CC;
    float a0 = p4[threadIdx.x], a1 = p4[threadIdx.x + 256];
    float b0 = p5[threadIdx.x], b1 = p5[threadIdx.x + 256];
    float y0 = b0 - largest * (a0 * rn);
    float y1 = b1 - largest * (a1 * rn);
    yp[threadIdx.x] = y0;
    yp[threadIdx.x + 256] = y1;
    float t = blk_reduce(y0 * y0 + y1 * y1, red);
    if (threadIdx.x == 0) { acc[b * 16 + 7] = t; acc[b * 16 + 8] = largest; }
}

__global__ void k_out(const float* __restrict__ acc, float* __restrict__ out) {
    int b = threadIdx.x;                   // 64 threads = 1 wave
    float largest = acc[b * 16 + 8];
    float dotwx   = acc[b * 16 + 9];
    float den2    = acc[b * 16 + 10];
    float tmp = (dotwx - largest * den2) / den2;
    float smallest = tmp + largest;
    float r = largest / smallest - 1.0f;
    float pen = r * r;                     // BETA = 1
    for (int off = 32; off; off >>= 1) pen += __shfl_down(pen, off, 64);
    if (b == 0) out[0] = pen / (float)BB;
}

extern "C" void kernel_launch(void* const* d_in, const int* in_sizes, int n_in,
                              void* d_out, int out_size, void* d_ws, size_t ws_size,
                              hipStream_t stream) {
    const float* A  = (const float*)d_in[0];
    const float* x0 = (const float*)d_in[1];
    float* out = (float*)d_out;
    float* ws = (float*)d_ws;

    float* acc = ws;                       // 1024 floats
    float* u1  = ws + 1024;                // 6 x BB*DD = 6 x 50176
    float* u2  = u1 + BB * DD;
    float* u3  = u2 + BB * DD;
    float* u4  = u3 + BB * DD;
    float* u5  = u4 + BB * DD;
    float* u6  = u5 + BB * DD;
    float* t1  = u6 + BB * DD;             // 6 x BB*CC = 6 x 32768
    float* t2  = t1 + BB * CC;
    float* t3  = t2 + BB * CC;
    float* t4  = t3 + BB * CC;             // unnormalized x1
    float* t5  = t4 + BB * CC;             // AAT x1
    float* y   = t5 + BB * CC;             // unnormalized x2

    // zero acc + u buffers (atomically accumulated); t/y are fully overwritten
    int nz = 1024 + 6 * BB * DD;           // 302080
    k_zero<<<(nz + 255) / 256, 256, 0, stream>>>(ws, nz);
    k_init<<<BB, 256, 0, stream>>>(x0, acc);

    dim3 gU(STRIPES, BB), gA(CC / 4, BB);

    k_u<<<gU, 256, 0, stream>>>(A, x0, acc, 0, u1);
    k_a<<<gA, 256, 0, stream>>>(A, u1, t1, acc, 0, 1, nullptr, 0);
    k_u<<<gU, 256, 0, stream>>>(A, t1, acc, 1, u2);
    k_a<<<gA, 256, 0, stream>>>(A, u2, t2, acc, 0, 2, nullptr, 0);
    k_u<<<gU, 256, 0, stream>>>(A, t2, acc, 2, u3);
    k_a<<<gA, 256, 0, stream>>>(A, u3, t3, acc, 0, 3, nullptr, 0);
    k_u<<<gU, 256, 0, stream>>>(A, t3, acc, 3, u4);
    k_a<<<gA, 256, 0, stream>>>(A, u4, t4, acc, 0, 4, nullptr, 0);

    // t5 = AAT x1; num = <t5, x1>, den = <x1,x1>
    k_u<<<gU, 256, 0, stream>>>(A, t4, acc, 4, u5);
    k_a<<<gA, 256, 0, stream>>>(A, u5, t5, acc, 1, 5, t4, 4);

    k_mid<<<BB, 256, 0, stream>>>(t4, t5, acc, y);

    // w = AAT x2; dotwx = <w,x2>, den2 = <x2,x2>
    k_u<<<gU, 256, 0, stream>>>(A, y, acc, 7, u6);
    k_a<<<gA, 256, 0, stream>>>(A, u6, nullptr, acc, 1, 9, y, 7);

    k_out<<<1, 64, 0, stream>>>(acc, out);
}